// Round 1
// baseline (280.535 us; speedup 1.0000x reference)
//
#include <hip/hip_runtime.h>
#include <hip/hip_bf16.h>

// Problem sizes (fixed)
#define B_    8
#define C_    256
#define NPIX  16384           // 128*128
#define KC    8               // K-chunks for gram partials
#define KCHUNK (NPIX / KC)    // 2048

typedef __attribute__((ext_vector_type(8))) short bf16x8;
typedef __attribute__((ext_vector_type(4))) float f32x4;

__device__ __forceinline__ unsigned short f2bf(float x) {
  unsigned int u = __builtin_bit_cast(unsigned int, x);
  u = (u + 0x7fffu + ((u >> 16) & 1u)) >> 16;   // RTNE
  return (unsigned short)u;
}
__device__ __forceinline__ float bf2f(unsigned short h) {
  unsigned int u = ((unsigned int)h) << 16;
  return __builtin_bit_cast(float, u);
}

// ---------------- k1: row sums  s[b*C+c] = sum_n X[b,c,n] ----------------
__global__ __launch_bounds__(256) void k_rowsum(const float* __restrict__ x,
                                                float* __restrict__ s) {
  const int row = blockIdx.x;                   // 0 .. B*C-1
  const float* xr = x + (size_t)row * NPIX;
  const int tid = threadIdx.x;
  float acc = 0.f;
#pragma unroll
  for (int i = 0; i < 16; ++i) {
    float4 v = *reinterpret_cast<const float4*>(xr + i * 1024 + tid * 4);
    acc += (v.x + v.y) + (v.z + v.w);
  }
#pragma unroll
  for (int off = 32; off; off >>= 1) acc += __shfl_xor(acc, off, 64);
  __shared__ float red[4];
  if ((tid & 63) == 0) red[tid >> 6] = acc;
  __syncthreads();
  if (tid == 0) s[row] = (red[0] + red[1]) + (red[2] + red[3]);
}

// ---------------- k2: Gram partials  G_part[b,kc] += X X^T over K-chunk ----
// grid: b(8) x ti(2) x tj(2) x kc(8) = 256 wgs; 128x128 tile, split-bf16 3-pass
__global__ __launch_bounds__(256) void k_gram(const float* __restrict__ x,
                                              float* __restrict__ gpart) {
  int bid = blockIdx.x;
  const int kc = bid & (KC - 1); bid >>= 3;
  const int tj = bid & 1;        bid >>= 1;
  const int ti = bid & 1;        bid >>= 1;
  const int b  = bid;
  const float* X = x + (size_t)b * C_ * NPIX;

  __shared__ __align__(16) unsigned short Ahi[128 * 64];
  __shared__ __align__(16) unsigned short Alo[128 * 64];
  __shared__ __align__(16) unsigned short Bhi[128 * 64];
  __shared__ __align__(16) unsigned short Blo[128 * 64];

  const int tid  = threadIdx.x;
  const int lane = tid & 63;
  const int w    = tid >> 6;
  const int wr   = w >> 1, wc = w & 1;

  f32x4 acc[4][4] = {};

  const int r = tid >> 1;        // staged row 0..127
  const int p = tid & 1;         // col half
  const float* arow = X + (size_t)(ti * 128 + r) * NPIX + kc * KCHUNK + p * 32;
  const float* brow = X + (size_t)(tj * 128 + r) * NPIX + kc * KCHUNK + p * 32;

  for (int ks = 0; ks < KCHUNK; ks += 64) {
    __syncthreads();
#pragma unroll
    for (int q = 0; q < 8; ++q) {
      const int col = p * 32 + q * 4;
      float4 va = *reinterpret_cast<const float4*>(arow + ks + q * 4);
      float4 vb = *reinterpret_cast<const float4*>(brow + ks + q * 4);
      const int idx = (r * 64 + col) ^ ((r & 7) << 3);
      ushort4 ah = make_ushort4(f2bf(va.x), f2bf(va.y), f2bf(va.z), f2bf(va.w));
      ushort4 al = make_ushort4(f2bf(va.x - bf2f(ah.x)), f2bf(va.y - bf2f(ah.y)),
                                f2bf(va.z - bf2f(ah.z)), f2bf(va.w - bf2f(ah.w)));
      ushort4 bh = make_ushort4(f2bf(vb.x), f2bf(vb.y), f2bf(vb.z), f2bf(vb.w));
      ushort4 bl = make_ushort4(f2bf(vb.x - bf2f(bh.x)), f2bf(vb.y - bf2f(bh.y)),
                                f2bf(vb.z - bf2f(bh.z)), f2bf(vb.w - bf2f(bh.w)));
      *reinterpret_cast<ushort4*>(&Ahi[idx]) = ah;
      *reinterpret_cast<ushort4*>(&Alo[idx]) = al;
      *reinterpret_cast<ushort4*>(&Bhi[idx]) = bh;
      *reinterpret_cast<ushort4*>(&Blo[idx]) = bl;
    }
    __syncthreads();
#pragma unroll
    for (int kk = 0; kk < 64; kk += 32) {
      bf16x8 ahi[4], alo[4], bhi[4], blo[4];
      const int kb = kk + (lane >> 4) * 8;
#pragma unroll
      for (int m = 0; m < 4; ++m) {
        const int rowa = wr * 64 + m * 16 + (lane & 15);
        const int ia = (rowa * 64 + kb) ^ ((rowa & 7) << 3);
        ahi[m] = *reinterpret_cast<const bf16x8*>(&Ahi[ia]);
        alo[m] = *reinterpret_cast<const bf16x8*>(&Alo[ia]);
        const int rowb = wc * 64 + m * 16 + (lane & 15);
        const int ib = (rowb * 64 + kb) ^ ((rowb & 7) << 3);
        bhi[m] = *reinterpret_cast<const bf16x8*>(&Bhi[ib]);
        blo[m] = *reinterpret_cast<const bf16x8*>(&Blo[ib]);
      }
#pragma unroll
      for (int m = 0; m < 4; ++m)
#pragma unroll
        for (int n = 0; n < 4; ++n) {
          acc[m][n] = __builtin_amdgcn_mfma_f32_16x16x32_bf16(ahi[m], bhi[n], acc[m][n], 0, 0, 0);
          acc[m][n] = __builtin_amdgcn_mfma_f32_16x16x32_bf16(ahi[m], blo[n], acc[m][n], 0, 0, 0);
          acc[m][n] = __builtin_amdgcn_mfma_f32_16x16x32_bf16(alo[m], bhi[n], acc[m][n], 0, 0, 0);
        }
    }
  }
  float* gp = gpart + (size_t)(b * KC + kc) * (C_ * C_);
#pragma unroll
  for (int m = 0; m < 4; ++m) {
    const int row0 = ti * 128 + wr * 64 + m * 16 + ((lane >> 4) << 2);
#pragma unroll
    for (int n = 0; n < 4; ++n) {
      const int col = tj * 128 + wc * 64 + n * 16 + (lane & 15);
#pragma unroll
      for (int j = 0; j < 4; ++j)
        gp[(size_t)(row0 + j) * C_ + col] = acc[m][n][j];
    }
  }
}

// ---------------- k3: reduce partials  G = sum_kc G_part ----------------
__global__ __launch_bounds__(256) void k_reduce(const float* __restrict__ gpart,
                                                float* __restrict__ g) {
  const size_t idx = (size_t)blockIdx.x * 256 + threadIdx.x;  // over B*65536
  const size_t b = idx >> 16;
  const size_t e = idx & 65535;
  float acc = 0.f;
#pragma unroll
  for (int kc = 0; kc < KC; ++kc) acc += gpart[(b * KC + kc) * 65536 + e];
  g[idx] = acc;
}

// ---------------- k4: 256x256 transpose (w2 -> w2t) ----------------
__global__ __launch_bounds__(256) void k_transpose(const float* __restrict__ in,
                                                   float* __restrict__ outp) {
  __shared__ float t[32][33];
  const int bx = blockIdx.x & 7, by = blockIdx.x >> 3;
  const int tx = threadIdx.x & 31, ty = threadIdx.x >> 5;  // 32 x 8
#pragma unroll
  for (int i = 0; i < 32; i += 8)
    t[ty + i][tx] = in[(size_t)(by * 32 + ty + i) * 256 + bx * 32 + tx];
  __syncthreads();
#pragma unroll
  for (int i = 0; i < 32; i += 8)
    outp[(size_t)(bx * 32 + ty + i) * 256 + by * 32 + tx] = t[tx][ty + i];
}

// ---------------- k5: u1 = W1 s, u2 = W2 s ----------------
__global__ __launch_bounds__(256) void k_u(const float* __restrict__ w1,
                                           const float* __restrict__ w2,
                                           const float* __restrict__ s,
                                           float* __restrict__ u1,
                                           float* __restrict__ u2) {
  const int b = blockIdx.x;
  const int tid = threadIdx.x;
  __shared__ float sl[256];
  sl[tid] = s[b * 256 + tid];
  __syncthreads();
  float a1 = 0.f, a2 = 0.f;
#pragma unroll 4
  for (int c = 0; c < 256; ++c) {
    a1 += w1[(size_t)tid * 256 + c] * sl[c];
    a2 += w2[(size_t)tid * 256 + c] * sl[c];
  }
  u1[b * 256 + tid] = a1;
  u2[b * 256 + tid] = a2;
}

// ---------------- k6: small f32 GEMM  C[i,j] = sum_k A[i,k] B[k,j] (256^3) ---
// grid (32, B): 8 output rows per block, 256 threads = 256 columns
__global__ __launch_bounds__(256) void k_smallmm(const float* __restrict__ A, long asb,
                                                 const float* __restrict__ Bm, long bsb,
                                                 float* __restrict__ Cm, long csb) {
  const int b  = blockIdx.y;
  const int i0 = blockIdx.x * 8;
  const float* Ab = A  + (size_t)asb * b;
  const float* Bb = Bm + (size_t)bsb * b;
  float*       Cb = Cm + (size_t)csb * b;
  const int tid = threadIdx.x;
  __shared__ float arows[8][256];
#pragma unroll
  for (int rr = 0; rr < 8; ++rr) arows[rr][tid] = Ab[(size_t)(i0 + rr) * 256 + tid];
  __syncthreads();
  float acc[8] = {};
#pragma unroll 4
  for (int k = 0; k < 256; ++k) {
    const float bv = Bb[(size_t)k * 256 + tid];
#pragma unroll
    for (int rr = 0; rr < 8; ++rr) acc[rr] += arows[rr][k] * bv;
  }
#pragma unroll
  for (int rr = 0; rr < 8; ++rr) Cb[(size_t)(i0 + rr) * 256 + tid] = acc[rr];
}

// ---------------- k7: logits finish + row softmax -> A (bf16) ----------------
__global__ __launch_bounds__(256) void k_softmax(const float* __restrict__ L,
                                                 const float* __restrict__ b1,
                                                 const float* __restrict__ b2,
                                                 const float* __restrict__ u1,
                                                 const float* __restrict__ u2,
                                                 unsigned short* __restrict__ Abf) {
  const int b = blockIdx.y, i = blockIdx.x, j = threadIdx.x;
  const size_t base = ((size_t)b * 256 + i) * 256;
  const float v = L[base + j] + u1[b * 256 + i] * b2[j] +
                  b1[i] * (u2[b * 256 + j] + 16384.f * b2[j]);
  const int lane = j & 63, wv = j >> 6;
  __shared__ float redm[4], reds[4];
  float m = v;
#pragma unroll
  for (int off = 32; off; off >>= 1) m = fmaxf(m, __shfl_xor(m, off, 64));
  if (lane == 0) redm[wv] = m;
  __syncthreads();
  m = fmaxf(fmaxf(redm[0], redm[1]), fmaxf(redm[2], redm[3]));
  const float e = __expf(v - m);
  float sm = e;
#pragma unroll
  for (int off = 32; off; off >>= 1) sm += __shfl_xor(sm, off, 64);
  if (lane == 0) reds[wv] = sm;
  __syncthreads();
  sm = (reds[0] + reds[1]) + (reds[2] + reds[3]);
  Abf[base + j] = f2bf(e / sm);
}

// ---------------- k8: out = x + A @ X  (MFMA, bf16) ----------------
// grid (NPIX/64, B); tile M=256(all c) x N=64, K=256, 4 waves x (64x64)
__global__ __launch_bounds__(256) void k_av(const unsigned short* __restrict__ Abf,
                                            const float* __restrict__ x,
                                            float* __restrict__ out) {
  const int n0 = blockIdx.x * 64;
  const int b  = blockIdx.y;
  const unsigned short* Ab = Abf + (size_t)b * 65536;
  const float* X   = x   + (size_t)b * C_ * NPIX;
  float*       Ob  = out + (size_t)b * C_ * NPIX;

  __shared__ __align__(16) unsigned short As[256 * 64];  // [c][d] swizzled
  __shared__ __align__(16) unsigned short Xt[64 * 64];   // [n][d] swizzled

  const int tid = threadIdx.x;
  const int lane = tid & 63, w = tid >> 6;
  f32x4 acc[4][4] = {};

  for (int d0 = 0; d0 < 256; d0 += 64) {
    __syncthreads();
    {  // stage A rows (bf16 already): thread = row, 8 x 16B
      const unsigned short* src = Ab + (size_t)tid * 256 + d0;
#pragma unroll
      for (int q = 0; q < 8; ++q) {
        uint4 v = *reinterpret_cast<const uint4*>(src + q * 8);
        const int idx = (tid * 64 + q * 8) ^ ((tid & 7) << 3);
        *reinterpret_cast<uint4*>(&As[idx]) = v;
      }
    }
    {  // stage X^T: one 4x4 f32 block per thread, transposed into [n][d]
      const int d = (tid >> 4) * 4, n = (tid & 15) * 4;
      const float* xs = X + (size_t)(d0 + d) * NPIX + n0 + n;
      float4 r0 = *reinterpret_cast<const float4*>(xs);
      float4 r1 = *reinterpret_cast<const float4*>(xs + NPIX);
      float4 r2 = *reinterpret_cast<const float4*>(xs + 2 * NPIX);
      float4 r3 = *reinterpret_cast<const float4*>(xs + 3 * NPIX);
      ushort4 c0 = make_ushort4(f2bf(r0.x), f2bf(r1.x), f2bf(r2.x), f2bf(r3.x));
      ushort4 c1 = make_ushort4(f2bf(r0.y), f2bf(r1.y), f2bf(r2.y), f2bf(r3.y));
      ushort4 c2 = make_ushort4(f2bf(r0.z), f2bf(r1.z), f2bf(r2.z), f2bf(r3.z));
      ushort4 c3 = make_ushort4(f2bf(r0.w), f2bf(r1.w), f2bf(r2.w), f2bf(r3.w));
      const int i0 = ((n + 0) * 64 + d) ^ (((n + 0) & 7) << 3);
      const int i1 = ((n + 1) * 64 + d) ^ (((n + 1) & 7) << 3);
      const int i2 = ((n + 2) * 64 + d) ^ (((n + 2) & 7) << 3);
      const int i3 = ((n + 3) * 64 + d) ^ (((n + 3) & 7) << 3);
      *reinterpret_cast<ushort4*>(&Xt[i0]) = c0;
      *reinterpret_cast<ushort4*>(&Xt[i1]) = c1;
      *reinterpret_cast<ushort4*>(&Xt[i2]) = c2;
      *reinterpret_cast<ushort4*>(&Xt[i3]) = c3;
    }
    __syncthreads();
#pragma unroll
    for (int kk = 0; kk < 64; kk += 32) {
      bf16x8 af[4], bq[4];
      const int kb = kk + (lane >> 4) * 8;
#pragma unroll
      for (int m = 0; m < 4; ++m) {
        const int rowa = w * 64 + m * 16 + (lane & 15);
        const int ia = (rowa * 64 + kb) ^ ((rowa & 7) << 3);
        af[m] = *reinterpret_cast<const bf16x8*>(&As[ia]);
        const int rowb = m * 16 + (lane & 15);
        const int ib = (rowb * 64 + kb) ^ ((rowb & 7) << 3);
        bq[m] = *reinterpret_cast<const bf16x8*>(&Xt[ib]);
      }
#pragma unroll
      for (int m = 0; m < 4; ++m)
#pragma unroll
        for (int n = 0; n < 4; ++n)
          acc[m][n] = __builtin_amdgcn_mfma_f32_16x16x32_bf16(af[m], bq[n], acc[m][n], 0, 0, 0);
    }
  }
  // epilogue: out = x + acc
#pragma unroll
  for (int m = 0; m < 4; ++m) {
    const int row0 = w * 64 + m * 16 + ((lane >> 4) << 2);
#pragma unroll
    for (int n = 0; n < 4; ++n) {
      const int col = n0 + n * 16 + (lane & 15);
#pragma unroll
      for (int j = 0; j < 4; ++j) {
        const size_t a = (size_t)(row0 + j) * NPIX + col;
        Ob[a] = X[a] + acc[m][n][j];
      }
    }
  }
}

extern "C" void kernel_launch(void* const* d_in, const int* in_sizes, int n_in,
                              void* d_out, int out_size, void* d_ws, size_t ws_size,
                              hipStream_t stream) {
  const float* x  = (const float*)d_in[0];
  const float* w1 = (const float*)d_in[1];
  const float* b1 = (const float*)d_in[2];
  const float* w2 = (const float*)d_in[3];
  const float* b2 = (const float*)d_in[4];
  float* out = (float*)d_out;
  char* ws = (char*)d_ws;

  // ws layout (bytes); total ~23.3 MB
  constexpr size_t GPART_OFF = 0;                         // 8*8*65536*4 = 16 MB
  constexpr size_t G_OFF     = GPART_OFF + (size_t)B_ * KC * C_ * C_ * 4;
  constexpr size_t T1_OFF    = G_OFF  + (size_t)B_ * C_ * C_ * 4;
  constexpr size_t L_OFF     = T1_OFF + (size_t)B_ * C_ * C_ * 4;
  constexpr size_t W2T_OFF   = L_OFF  + (size_t)B_ * C_ * C_ * 4;
  constexpr size_t S_OFF     = W2T_OFF + (size_t)C_ * C_ * 4;
  constexpr size_t U1_OFF    = S_OFF  + (size_t)B_ * C_ * 4;
  constexpr size_t U2_OFF    = U1_OFF + (size_t)B_ * C_ * 4;
  constexpr size_t ABF_OFF   = U2_OFF + (size_t)B_ * C_ * 4;

  float* gpart = (float*)(ws + GPART_OFF);
  float* G     = (float*)(ws + G_OFF);
  float* T1    = (float*)(ws + T1_OFF);
  float* L     = (float*)(ws + L_OFF);
  float* w2t   = (float*)(ws + W2T_OFF);
  float* s     = (float*)(ws + S_OFF);
  float* u1    = (float*)(ws + U1_OFF);
  float* u2    = (float*)(ws + U2_OFF);
  unsigned short* Abf = (unsigned short*)(ws + ABF_OFF);

  k_rowsum   <<<B_ * C_, 256, 0, stream>>>(x, s);
  k_transpose<<<64, 256, 0, stream>>>(w2, w2t);
  k_gram     <<<B_ * 4 * KC, 256, 0, stream>>>(x, gpart);
  k_reduce   <<<(B_ * C_ * C_) / 256, 256, 0, stream>>>(gpart, G);
  k_u        <<<B_, 256, 0, stream>>>(w1, w2, s, u1, u2);
  // T1 = W1 @ G   (A unbatched, B/C batched)
  k_smallmm  <<<dim3(32, B_), 256, 0, stream>>>(w1, 0, G, C_ * C_, T1, C_ * C_);
  // L = T1 @ W2^T = T1 @ w2t  (A/C batched, B unbatched)
  k_smallmm  <<<dim3(32, B_), 256, 0, stream>>>(T1, C_ * C_, w2t, 0, L, C_ * C_);
  k_softmax  <<<dim3(C_, B_), 256, 0, stream>>>(L, b1, b2, u1, u2, Abf);
  k_av       <<<dim3(NPIX / 64, B_), 256, 0, stream>>>(Abf, x, out);
}